// Round 11
// baseline (23.362 us; speedup 1.0000x reference)
//
#include <hip/hip_runtime.h>
#include <math.h>

#define BATCH   512
#define IN_DIM  256
#define OUT_DIM 256
#define NDEG    6     // degree+1

// R11 geometry: 256 threads = 8 o-lanes x 32 i-segments; NB=16 b-accs per
// thread (coef reuse 16x -> halves L2/L1 coefficient traffic vs NB=8);
// grid (32,32) = 1024 blocks = 4 blocks/CU.  Software pipeline: g0 coef
// loads issued BEFORE t-staging (latency hidden under exp+LDS-write),
// g1 loads issued right after the barrier BEFORE g0 compute (hidden under
// g0's compute) -- removes the lockstep load-burst/compute serialization
// that R10's post-mortem identified as the residual bottleneck.
#define OT     8     // o per block
#define NSEG   32    // i-segments per block (tid>>3)
#define ISEG   8     // i's per segment
#define NB     16    // b per block (register accumulators)

typedef float v2f __attribute__((ext_vector_type(2)));

// d = a * broadcast(lo32(t)) + c
__device__ __forceinline__ v2f pk_fma_blo(v2f a, v2f t, v2f c) {
    v2f d;
    asm("v_pk_fma_f32 %0, %1, %2, %3 op_sel:[0,0,0] op_sel_hi:[1,0,1]"
        : "=v"(d) : "v"(a), "v"(t), "v"(c));
    return d;
}
// d = a * broadcast(hi32(t)) + c
__device__ __forceinline__ v2f pk_fma_bhi(v2f a, v2f t, v2f c) {
    v2f d;
    asm("v_pk_fma_f32 %0, %1, %2, %3 op_sel:[0,1,0] op_sel_hi:[1,1,1]"
        : "=v"(d) : "v"(a), "v"(t), "v"(c));
    return d;
}
__device__ __forceinline__ v2f pk_mul(v2f a, v2f b) {
    v2f d;
    asm("v_pk_mul_f32 %0, %1, %2" : "=v"(d) : "v"(a), "v"(b));
    return d;
}

#define PRESCALE 12.476649250079015f   // 18 * ln2

// pk2 layout (R7 lane-ordered): slab (o_blk*4 + wv), steps k = ii*3 + w,
// each step = 64 contiguous float4 (one per lane).
// float4 word w: (p_{2w}, q_{2w}, p_{2w+1}, q_{2w+1}), coefs = exp(w - 18ln2).
__global__ void prep_pack(const float* __restrict__ wp,
                          const float* __restrict__ wq,
                          float4* __restrict__ pk2) {
    int j = blockIdx.x * blockDim.x + threadIdx.x;   // j = i*OUT_DIM + o
    if (j >= IN_DIM * OUT_DIM) return;
    const int i = j >> 8, o = j & 255;
    const int seg_blk = i >> 6;
    const int seg     = (i >> 3) & 7;
    const int ii      = i & 7;
    const int o_blk   = o >> 3;
    const int o_l     = o & 7;
    const size_t base =
        ((size_t)(o_blk * 4 + seg_blk) * 24) * 64 + seg * 8 + o_l;

    const float2* wp2 = (const float2*)wp;
    const float2* wq2 = (const float2*)wq;
    float2 p0 = wp2[j * 3], p1 = wp2[j * 3 + 1], p2 = wp2[j * 3 + 2];
    float2 q0 = wq2[j * 3], q1 = wq2[j * 3 + 1], q2 = wq2[j * 3 + 2];
    pk2[base + (ii * 3 + 0) * 64] =
        make_float4(__expf(p0.x - PRESCALE), __expf(q0.x - PRESCALE),
                    __expf(p0.y - PRESCALE), __expf(q0.y - PRESCALE));
    pk2[base + (ii * 3 + 1) * 64] =
        make_float4(__expf(p1.x - PRESCALE), __expf(q1.x - PRESCALE),
                    __expf(p1.y - PRESCALE), __expf(q1.y - PRESCALE));
    pk2[base + (ii * 3 + 2) * 64] =
        make_float4(__expf(p2.x - PRESCALE), __expf(q2.x - PRESCALE),
                    __expf(p2.y - PRESCALE), __expf(q2.y - PRESCALE));
}

// Packed Horner, t broadcast straight from a (t0,t1) register pair via op_sel.
__device__ __forceinline__ v2f horner_lo(float4 c0, float4 c1, float4 c2, v2f tp) {
    const v2f C0 = {c0.x, c0.y}, C1 = {c0.z, c0.w};
    const v2f C2 = {c1.x, c1.y}, C3 = {c1.z, c1.w};
    const v2f C4 = {c2.x, c2.y}, C5 = {c2.z, c2.w};
    v2f r = pk_fma_blo(C5, tp, C4);
    r = pk_fma_blo(r, tp, C3);
    r = pk_fma_blo(r, tp, C2);
    r = pk_fma_blo(r, tp, C1);
    r = pk_fma_blo(r, tp, C0);
    return r;
}
__device__ __forceinline__ v2f horner_hi(float4 c0, float4 c1, float4 c2, v2f tp) {
    const v2f C0 = {c0.x, c0.y}, C1 = {c0.z, c0.w};
    const v2f C2 = {c1.x, c1.y}, C3 = {c1.z, c1.w};
    const v2f C4 = {c2.x, c2.y}, C5 = {c2.z, c2.w};
    v2f r = pk_fma_bhi(C5, tp, C4);
    r = pk_fma_bhi(r, tp, C3);
    r = pk_fma_bhi(r, tp, C2);
    r = pk_fma_bhi(r, tp, C1);
    r = pk_fma_bhi(r, tp, C0);
    return r;
}

// One 4-i batch: Horner x4 + product + batched log2 into acc[b].
#define BATCH4(Cv, b, g)                                                      \
    {                                                                         \
        const float4 tv = *(const float4*)(tb + (b) * IN_DIM + (g) * 4);      \
        const v2f txy = {tv.x, tv.y};                                         \
        const v2f tzw = {tv.z, tv.w};                                         \
        const v2f PQ0 = horner_lo(Cv[0], Cv[1],  Cv[2],  txy);                \
        const v2f PQ1 = horner_hi(Cv[3], Cv[4],  Cv[5],  txy);                \
        const v2f PQ2 = horner_lo(Cv[6], Cv[7],  Cv[8],  tzw);                \
        const v2f PQ3 = horner_hi(Cv[9], Cv[10], Cv[11], tzw);                \
        const v2f m = pk_mul(pk_mul(PQ0, PQ1), pk_mul(PQ2, PQ3));             \
        acc[b] += __log2f(m.x) - __log2f(m.y);                                \
    }

// Grid = (OUT_DIM/OT = 32, BATCH/NB = 32) = 1024 blocks = 4/CU.
__launch_bounds__(256, 4)
__global__ void tropical_main(const float* __restrict__ x,
                              const float4* __restrict__ pk2,
                              float* __restrict__ out) {
    // Phase A: t[b][i], 16 b x 256 i (4096 f). Phase B: reduce buffer,
    // NSEG slabs of stride NB*OT+1 = 129 (4128 f). Shared allocation.
    __shared__ float lds[NSEG * (NB * OT + 1)];   // 4128 floats = 16.5 KiB

    const int tid = threadIdx.x;
    const int o_l = tid & (OT - 1);
    const int b0  = blockIdx.y * NB;

    const int lane = tid & 63;
    const int wv   = tid >> 6;
    const float4* __restrict__ cb =
        pk2 + ((size_t)(blockIdx.x * 4 + wv) * 24) * 64 + lane;

    // ---- issue group-0 coefficient loads FIRST (hide under staging) ----
    float4 C0[12];
#pragma unroll
    for (int k = 0; k < 12; ++k)
        C0[k] = cb[k * 64];

    // ---- stage t = exp(x): 16 b-rows x 256 i (16 floats / thread) ----
    {
        const int r = tid >> 4;            // 0..15
        const int c = (tid & 15) * 16;     // 0..240
        const float* xr = x + (size_t)(b0 + r) * IN_DIM + c;
#pragma unroll
        for (int q = 0; q < 4; ++q) {
            const float4 v = *(const float4*)(xr + q * 4);
            float4 w;
            w.x = __expf(v.x); w.y = __expf(v.y);
            w.z = __expf(v.z); w.w = __expf(v.w);
            *(float4*)&lds[r * IN_DIM + c + q * 4] = w;
        }
    }
    __syncthreads();

    // ---- issue group-1 loads BEFORE g0 compute (hide under g0 math) ----
    float4 C1[12];
#pragma unroll
    for (int k = 0; k < 12; ++k)
        C1[k] = cb[(12 + k) * 64];

    float acc[NB];
#pragma unroll
    for (int b = 0; b < NB; ++b) acc[b] = 0.f;

    const int i0 = (tid >> 3) * ISEG;
    const float* __restrict__ tb = lds + i0;

#pragma unroll
    for (int b = 0; b < NB; ++b)
        BATCH4(C0, b, 0);
#pragma unroll
    for (int b = 0; b < NB; ++b)
        BATCH4(C1, b, 1);

    __syncthreads();   // done with t; reuse LDS as reduce buffer
    const int seg = tid >> 3;
#pragma unroll
    for (int b = 0; b < NB; ++b)
        lds[seg * (NB * OT + 1) + b * OT + o_l] = acc[b];
    __syncthreads();

    if (tid < NB * OT) {                   // 128 threads
        const int br = tid >> 3, orr = tid & (OT - 1);
        float s = 0.f;
#pragma unroll
        for (int g = 0; g < NSEG; ++g)
            s += lds[g * (NB * OT + 1) + br * OT + orr];
        out[(size_t)(b0 + br) * OUT_DIM + blockIdx.x * OT + orr] =
            s * 0.6931471805599453f;   // * ln2
    }
}

// Fallback (workspace too small): direct stabilized LSE.
__global__ void tropical_fallback(const float* __restrict__ x,
                                  const float* __restrict__ wp,
                                  const float* __restrict__ wq,
                                  float* __restrict__ out) {
    const int o = blockIdx.x * 16 + (threadIdx.x & 15);
    const int b = blockIdx.y * 16 + (threadIdx.x >> 4);
    float acc = 0.f;
    for (int i = 0; i < IN_DIM; ++i) {
        const float xv = x[b * IN_DIM + i];
        const float* p = wp + (size_t)(i * OUT_DIM + o) * NDEG;
        const float* q = wq + (size_t)(i * OUT_DIM + o) * NDEG;
        float lp[NDEG], lq[NDEG], mP = -1e30f, mQ = -1e30f;
#pragma unroll
        for (int d = 0; d < NDEG; ++d) {
            lp[d] = xv * d + p[d]; mP = fmaxf(mP, lp[d]);
            lq[d] = xv * d + q[d]; mQ = fmaxf(mQ, lq[d]);
        }
        float sP = 0.f, sQ = 0.f;
#pragma unroll
        for (int d = 0; d < NDEG; ++d) {
            sP += __expf(lp[d] - mP);
            sQ += __expf(lq[d] - mQ);
        }
        acc += (mP + __logf(sP)) - (mQ + __logf(sQ));
    }
    out[b * OUT_DIM + o] = acc;
}

extern "C" void kernel_launch(void* const* d_in, const int* in_sizes, int n_in,
                              void* d_out, int out_size, void* d_ws, size_t ws_size,
                              hipStream_t stream) {
    const float* x  = (const float*)d_in[0];
    // d_in[1] = slopes (arange(6)) — implicit in the polynomial powers.
    const float* wp = (const float*)d_in[2];
    const float* wq = (const float*)d_in[3];
    float* out = (float*)d_out;

    const size_t pk_bytes = (size_t)IN_DIM * OUT_DIM * 12 * sizeof(float);  // 3 MiB

    if (ws_size >= pk_bytes) {
        float4* pk2 = (float4*)d_ws;
        prep_pack<<<(IN_DIM * OUT_DIM + 255) / 256, 256, 0, stream>>>(wp, wq, pk2);

        dim3 grid(OUT_DIM / OT, BATCH / NB);   // 32 x 32 = 1024 blocks
        tropical_main<<<grid, 256, 0, stream>>>(x, (const float4*)pk2, out);
    } else {
        dim3 grid(OUT_DIM / 16, BATCH / 16);
        tropical_fallback<<<grid, 256, 0, stream>>>(x, wp, wq, out);
    }
}